// Round 1
// baseline (141.147 us; speedup 1.0000x reference)
//
#include <hip/hip_runtime.h>

#define DIMV 16
#define NSTEP 4095      // 4096 - 1 increments
#define NC 64           // chunks
#define TSTEP 64        // ceil(NSTEP / NC)
#define SIG13 4368      // 16 + 256 + 4096
#define L4 65536        // 16^4

// ---------------- dx = diff(x) ----------------
__global__ void k_dx(const float* __restrict__ x, float* __restrict__ dx) {
    int i = blockIdx.x * blockDim.x + threadIdx.x;
    if (i < NSTEP * DIMV) dx[i] = x[i + DIMV] - x[i];
}

// ------------- per-chunk signature, levels 1-3, from zero -------------
// thread t owns ab = t (a = t>>4, b = t&15); state fully in registers.
__global__ __launch_bounds__(256) void k_chunk_sig(const float* __restrict__ dx,
                                                   float* __restrict__ chunk_sig) {
    const int c = blockIdx.x;
    const int t = threadIdx.x;
    const int a = t >> 4, b = t & 15;
    float A1a = 0.f, A2 = 0.f;
    float A3[16];
#pragma unroll
    for (int j = 0; j < 16; ++j) A3[j] = 0.f;

    const int s0 = c * TSTEP;
    const int s1 = (s0 + TSTEP < NSTEP) ? (s0 + TSTEP) : NSTEP;
    for (int s = s0; s < s1; ++s) {
        const float* row = dx + s * DIMV;
        const float4* r4 = reinterpret_cast<const float4*>(row);
        float4 q0 = r4[0], q1 = r4[1], q2 = r4[2], q3 = r4[3];
        float dxv[16] = {q0.x,q0.y,q0.z,q0.w, q1.x,q1.y,q1.z,q1.w,
                         q2.x,q2.y,q2.z,q2.w, q3.x,q3.y,q3.z,q3.w};
        float dxa = row[a];            // scalar loads avoid runtime-indexed reg array
        float dxb = row[b];
        float V2 = fmaf(dxb, fmaf(dxa, 1.f/6.f, 0.5f * A1a), A2);
        float h2 = fmaf(dxa, 0.5f, A1a);
#pragma unroll
        for (int j = 0; j < 16; ++j) A3[j] = fmaf(dxv[j], V2, A3[j]);
        A2 = fmaf(dxb, h2, A2);
        A1a += dxa;
    }
    float* o = chunk_sig + c * SIG13;
    if (b == 0) o[a] = A1a;
    o[16 + t] = A2;
    float4* o4 = reinterpret_cast<float4*>(o + 272 + t * 16);
    o4[0] = make_float4(A3[0], A3[1], A3[2], A3[3]);
    o4[1] = make_float4(A3[4], A3[5], A3[6], A3[7]);
    o4[2] = make_float4(A3[8], A3[9], A3[10], A3[11]);
    o4[3] = make_float4(A3[12], A3[13], A3[14], A3[15]);
}

// ------------- sequential exclusive prefix over chunk sigs (Chen combine) -------------
// Also writes final levels 1-3 into out13 (= d_out[0..4368)).
__global__ __launch_bounds__(256) void k_prefix(const float* __restrict__ chunk_sig,
                                                float* __restrict__ prefix_sig,
                                                float* __restrict__ out13) {
    const int t = threadIdx.x;
    const int a = t >> 4, b = t & 15;
    float P1a = 0.f, P2 = 0.f;
    float P3[16];
#pragma unroll
    for (int j = 0; j < 16; ++j) P3[j] = 0.f;

    for (int c = 0; c < NC; ++c) {
        float* pre = prefix_sig + c * SIG13;
        if (b == 0) pre[a] = P1a;
        pre[16 + t] = P2;
        float4* p4 = reinterpret_cast<float4*>(pre + 272 + t * 16);
        p4[0] = make_float4(P3[0], P3[1], P3[2], P3[3]);
        p4[1] = make_float4(P3[4], P3[5], P3[6], P3[7]);
        p4[2] = make_float4(P3[8], P3[9], P3[10], P3[11]);
        p4[3] = make_float4(P3[12], P3[13], P3[14], P3[15]);

        const float* B = chunk_sig + c * SIG13;
        const float4* b1 = reinterpret_cast<const float4*>(B);
        float4 u0 = b1[0], u1 = b1[1], u2 = b1[2], u3 = b1[3];
        float B1[16] = {u0.x,u0.y,u0.z,u0.w, u1.x,u1.y,u1.z,u1.w,
                        u2.x,u2.y,u2.z,u2.w, u3.x,u3.y,u3.z,u3.w};
        float B1a = B[a], B1b = B[b];
        const float4* b2 = reinterpret_cast<const float4*>(B + 16 + b * 16);
        float4 v0 = b2[0], v1 = b2[1], v2 = b2[2], v3 = b2[3];
        float B2row[16] = {v0.x,v0.y,v0.z,v0.w, v1.x,v1.y,v1.z,v1.w,
                           v2.x,v2.y,v2.z,v2.w, v3.x,v3.y,v3.z,v3.w};
        float B2own = B[16 + t];
        const float4* b3 = reinterpret_cast<const float4*>(B + 272 + t * 16);
        float4 w0 = b3[0], w1 = b3[1], w2 = b3[2], w3 = b3[3];
        float B3own[16] = {w0.x,w0.y,w0.z,w0.w, w1.x,w1.y,w1.z,w1.w,
                           w2.x,w2.y,w2.z,w2.w, w3.x,w3.y,w3.z,w3.w};

        float nP2 = P2 + B2own + P1a * B1b;
#pragma unroll
        for (int j = 0; j < 16; ++j)
            P3[j] = P3[j] + B3own[j] + fmaf(P1a, B2row[j], P2 * B1[j]);
        P2 = nP2;
        P1a += B1a;
    }
    if (b == 0) out13[a] = P1a;
    out13[16 + t] = P2;
    float4* o4 = reinterpret_cast<float4*>(out13 + 272 + t * 16);
    o4[0] = make_float4(P3[0], P3[1], P3[2], P3[3]);
    o4[1] = make_float4(P3[4], P3[5], P3[6], P3[7]);
    o4[2] = make_float4(P3[8], P3[9], P3[10], P3[11]);
    o4[3] = make_float4(P3[12], P3[13], P3[14], P3[15]);
}

// ------------- level-4 accumulation: re-scan chunk from true prefix -------------
// block (c, g): chunk c, d-group g (4 d values). acc[c-index][d] in registers.
template <bool ATOMIC>
__global__ __launch_bounds__(256) void k_scan4(const float* __restrict__ dx,
                                               const float* __restrict__ prefix_sig,
                                               float* __restrict__ dst) {
    const int c = blockIdx.x;
    const int g = blockIdx.y;   // 0..3
    const int t = threadIdx.x;
    const int a = t >> 4, b = t & 15;

    const float* P = prefix_sig + c * SIG13;
    float A1a = P[a];
    float A2 = P[16 + t];
    const float4* p3 = reinterpret_cast<const float4*>(P + 272 + t * 16);
    float4 e0 = p3[0], e1 = p3[1], e2 = p3[2], e3 = p3[3];
    float A3[16] = {e0.x,e0.y,e0.z,e0.w, e1.x,e1.y,e1.z,e1.w,
                    e2.x,e2.y,e2.z,e2.w, e3.x,e3.y,e3.z,e3.w};
    float acc[16][4];
#pragma unroll
    for (int j = 0; j < 16; ++j)
#pragma unroll
        for (int dd = 0; dd < 4; ++dd) acc[j][dd] = 0.f;

    const int s0 = c * TSTEP;
    const int s1 = (s0 + TSTEP < NSTEP) ? (s0 + TSTEP) : NSTEP;
    for (int s = s0; s < s1; ++s) {
        const float* row = dx + s * DIMV;
        const float4* r4 = reinterpret_cast<const float4*>(row);
        float4 q0 = r4[0], q1 = r4[1], q2 = r4[2], q3 = r4[3];
        float dxv[16] = {q0.x,q0.y,q0.z,q0.w, q1.x,q1.y,q1.z,q1.w,
                         q2.x,q2.y,q2.z,q2.w, q3.x,q3.y,q3.z,q3.w};
        float dxa = row[a];
        float dxb = row[b];
        float4 qd = *reinterpret_cast<const float4*>(row + g * 4);

        float U2 = fmaf(dxb, fmaf(dxa, 1.f/24.f, A1a * (1.f/6.f)), 0.5f * A2);
        float V2 = fmaf(dxb, fmaf(dxa, 1.f/6.f, A1a * 0.5f), A2);
        float h2 = fmaf(dxa, 0.5f, A1a);
#pragma unroll
        for (int j = 0; j < 16; ++j) {
            float u3 = fmaf(dxv[j], U2, A3[j]);
            acc[j][0] = fmaf(u3, qd.x, acc[j][0]);
            acc[j][1] = fmaf(u3, qd.y, acc[j][1]);
            acc[j][2] = fmaf(u3, qd.z, acc[j][2]);
            acc[j][3] = fmaf(u3, qd.w, acc[j][3]);
            A3[j] = fmaf(dxv[j], V2, A3[j]);
        }
        A2 = fmaf(dxb, h2, A2);
        A1a += dxa;
    }

    if (ATOMIC) {
        float* o = dst + t * 256 + g * 4;
#pragma unroll
        for (int j = 0; j < 16; ++j) {
            atomicAdd(o + j * 16 + 0, acc[j][0]);
            atomicAdd(o + j * 16 + 1, acc[j][1]);
            atomicAdd(o + j * 16 + 2, acc[j][2]);
            atomicAdd(o + j * 16 + 3, acc[j][3]);
        }
    } else {
        float* o = dst + (size_t)c * L4 + t * 256 + g * 4;
#pragma unroll
        for (int j = 0; j < 16; ++j)
            *reinterpret_cast<float4*>(o + j * 16) =
                make_float4(acc[j][0], acc[j][1], acc[j][2], acc[j][3]);
    }
}

// ------------- sum per-chunk level-4 partials -------------
__global__ __launch_bounds__(256) void k_reduce4(const float* __restrict__ partials,
                                                 float* __restrict__ out4) {
    const int i = blockIdx.x * 256 + threadIdx.x;  // 0..65535
    float s = 0.f;
#pragma unroll 8
    for (int c = 0; c < NC; ++c) s += partials[(size_t)c * L4 + i];
    out4[i] = s;
}

extern "C" void kernel_launch(void* const* d_in, const int* in_sizes, int n_in,
                              void* d_out, int out_size, void* d_ws, size_t ws_size,
                              hipStream_t stream) {
    const float* x = (const float*)d_in[0];
    float* out = (float*)d_out;
    float* ws = (float*)d_ws;

    float* dx = ws;                                   // 65536 floats (65520 used)
    float* chunk_sig = ws + 65536;                    // NC * SIG13
    float* prefix_sig = chunk_sig + NC * SIG13;       // NC * SIG13
    float* partials = prefix_sig + NC * SIG13;        // NC * L4
    const size_t need_bytes =
        ((size_t)65536 + 2ull * NC * SIG13 + (size_t)NC * L4) * sizeof(float);

    k_dx<<<dim3((NSTEP * DIMV + 255) / 256), dim3(256), 0, stream>>>(x, dx);
    k_chunk_sig<<<dim3(NC), dim3(256), 0, stream>>>(dx, chunk_sig);
    k_prefix<<<dim3(1), dim3(256), 0, stream>>>(chunk_sig, prefix_sig, out);

    if (ws_size >= need_bytes) {
        k_scan4<false><<<dim3(NC, 4), dim3(256), 0, stream>>>(dx, prefix_sig, partials);
        k_reduce4<<<dim3(256), dim3(256), 0, stream>>>(partials, out + SIG13);
    } else {
        hipMemsetAsync(out + SIG13, 0, (size_t)L4 * sizeof(float), stream);
        k_scan4<true><<<dim3(NC, 4), dim3(256), 0, stream>>>(dx, prefix_sig, out + SIG13);
    }
}

// Round 2
// 137.646 us; speedup vs baseline: 1.0254x; 1.0254x over previous
//
#include <hip/hip_runtime.h>

#define DIMV 16
#define NSTEP 4095      // 4096 - 1 increments
#define NC 64           // chunks
#define TSTEP 64        // ceil(NSTEP / NC)
#define SIG13 4368      // 16 + 256 + 4096
#define L4 65536        // 16^4

// 16-wide register vector as 4 explicit float4s — never runtime-indexed,
// so it can never be demoted to scratch (learned: round-1 k_prefix VGPR=36 spill).
struct V16 { float4 a, b, c, d; };

#define EACH(OP) OP(a,x) OP(a,y) OP(a,z) OP(a,w) OP(b,x) OP(b,y) OP(b,z) OP(b,w) \
                 OP(c,x) OP(c,y) OP(c,z) OP(c,w) OP(d,x) OP(d,y) OP(d,z) OP(d,w)
#define EACHI(OP) OP(0,a,x) OP(1,a,y) OP(2,a,z) OP(3,a,w) \
                  OP(4,b,x) OP(5,b,y) OP(6,b,z) OP(7,b,w) \
                  OP(8,c,x) OP(9,c,y) OP(10,c,z) OP(11,c,w) \
                  OP(12,d,x) OP(13,d,y) OP(14,d,z) OP(15,d,w)

__device__ inline V16 ldv16(const float* p) {
    const float4* q = reinterpret_cast<const float4*>(p);
    V16 v; v.a = q[0]; v.b = q[1]; v.c = q[2]; v.d = q[3]; return v;
}
__device__ inline void stv16(float* p, const V16& v) {
    float4* q = reinterpret_cast<float4*>(p);
    q[0] = v.a; q[1] = v.b; q[2] = v.c; q[3] = v.d;
}
__device__ inline V16 zerov16() {
    V16 v; v.a = v.b = v.c = v.d = make_float4(0.f, 0.f, 0.f, 0.f); return v;
}

// ---------------- dx = diff(x) ----------------
__global__ void k_dx(const float* __restrict__ x, float* __restrict__ dx) {
    int i = blockIdx.x * blockDim.x + threadIdx.x;
    if (i < NSTEP * DIMV) dx[i] = x[i + DIMV] - x[i];
}

// ------------- per-chunk signature, levels 1-3, from zero -------------
__global__ __launch_bounds__(256, 1) void k_chunk_sig(const float* __restrict__ dx,
                                                      float* __restrict__ chunk_sig) {
    const int cb = blockIdx.x;
    const int t = threadIdx.x;
    const int ia = t >> 4, ib = t & 15;
    float A1a = 0.f, A2 = 0.f;
    V16 A3 = zerov16();

    const int s0 = cb * TSTEP;
    const int s1 = (s0 + TSTEP < NSTEP) ? (s0 + TSTEP) : NSTEP;
    for (int s = s0; s < s1; ++s) {
        const float* row = dx + s * DIMV;
        V16 dxv = ldv16(row);
        float dxa = row[ia];
        float dxb = row[ib];
        float V2 = fmaf(dxb, fmaf(dxa, 1.f/6.f, 0.5f * A1a), A2);
        float h2 = fmaf(dxa, 0.5f, A1a);
#define CS(Q,C) A3.Q.C = fmaf(dxv.Q.C, V2, A3.Q.C);
        EACH(CS)
#undef CS
        A2 = fmaf(dxb, h2, A2);
        A1a += dxa;
    }
    float* o = chunk_sig + cb * SIG13;
    if (ib == 0) o[ia] = A1a;
    o[16 + t] = A2;
    stv16(o + 272 + t * 16, A3);
}

// ------------- sequential exclusive prefix over chunk sigs (Chen combine) -------------
__device__ inline void load_buf(const float* B, int ia, int ib, int t,
                                V16& b1, V16& b2r, V16& b3,
                                float& b1a, float& b1b, float& b2o) {
    b1  = ldv16(B);
    b1a = B[ia];
    b1b = B[ib];
    b2r = ldv16(B + 16 + ib * 16);
    b2o = B[16 + t];
    b3  = ldv16(B + 272 + t * 16);
}

__device__ inline void combine(float& P1a, float& P2, V16& P3,
                               const V16& b1, const V16& b2r, const V16& b3,
                               float b1a, float b1b, float b2o) {
#define CMB(Q,C) P3.Q.C += fmaf(P1a, b2r.Q.C, fmaf(P2, b1.Q.C, b3.Q.C));
    EACH(CMB)
#undef CMB
    P2 = P2 + b2o + P1a * b1b;
    P1a += b1a;
}

__device__ inline void store_state(float* p, int ia, int ib, int t,
                                   float P1a, float P2, const V16& P3) {
    if (ib == 0) p[ia] = P1a;
    p[16 + t] = P2;
    stv16(p + 272 + t * 16, P3);
}

__global__ __launch_bounds__(256, 1) void k_prefix(const float* __restrict__ chunk_sig,
                                                   float* __restrict__ prefix_sig,
                                                   float* __restrict__ out13) {
    const int t = threadIdx.x;
    const int ia = t >> 4, ib = t & 15;
    float P1a = 0.f, P2 = 0.f;
    V16 P3 = zerov16();

    V16 Ab1, Ab2r, Ab3;  float Ab1a, Ab1b, Ab2o;
    V16 Bb1, Bb2r, Bb3;  float Bb1a, Bb1b, Bb2o;
    load_buf(chunk_sig,          ia, ib, t, Ab1, Ab2r, Ab3, Ab1a, Ab1b, Ab2o);
    load_buf(chunk_sig + SIG13,  ia, ib, t, Bb1, Bb2r, Bb3, Bb1a, Bb1b, Bb2o);

    for (int c = 0; c < NC; c += 2) {
        store_state(prefix_sig + (size_t)c * SIG13, ia, ib, t, P1a, P2, P3);
        combine(P1a, P2, P3, Ab1, Ab2r, Ab3, Ab1a, Ab1b, Ab2o);
        {
            int nc = c + 2 < NC ? c + 2 : NC - 1;   // clamped: dead load at tail
            load_buf(chunk_sig + (size_t)nc * SIG13, ia, ib, t,
                     Ab1, Ab2r, Ab3, Ab1a, Ab1b, Ab2o);
        }
        store_state(prefix_sig + (size_t)(c + 1) * SIG13, ia, ib, t, P1a, P2, P3);
        combine(P1a, P2, P3, Bb1, Bb2r, Bb3, Bb1a, Bb1b, Bb2o);
        {
            int nc = c + 3 < NC ? c + 3 : NC - 1;
            load_buf(chunk_sig + (size_t)nc * SIG13, ia, ib, t,
                     Bb1, Bb2r, Bb3, Bb1a, Bb1b, Bb2o);
        }
    }
    store_state(out13, ia, ib, t, P1a, P2, P3);
}

// ------------- level-4 accumulation: re-scan chunk from true prefix -------------
template <bool ATOMIC>
__global__ __launch_bounds__(256, 1) void k_scan4(const float* __restrict__ dx,
                                                  const float* __restrict__ prefix_sig,
                                                  float* __restrict__ dst) {
    const int cb = blockIdx.x;
    const int g = blockIdx.y;   // 0..3 : d-group
    const int t = threadIdx.x;
    const int ia = t >> 4, ib = t & 15;

    const float* P = prefix_sig + (size_t)cb * SIG13;
    float A1a = P[ia];
    float A2 = P[16 + t];
    V16 A3 = ldv16(P + 272 + t * 16);
    V16 ac0 = zerov16(), ac1 = zerov16(), ac2 = zerov16(), ac3 = zerov16();

    const int s0 = cb * TSTEP;
    const int s1 = (s0 + TSTEP < NSTEP) ? (s0 + TSTEP) : NSTEP;
    for (int s = s0; s < s1; ++s) {
        const float* row = dx + s * DIMV;
        V16 dxv = ldv16(row);
        float dxa = row[ia];
        float dxb = row[ib];
        float4 qd = *reinterpret_cast<const float4*>(row + g * 4);

        float U2 = fmaf(dxb, fmaf(dxa, 1.f/24.f, A1a * (1.f/6.f)), 0.5f * A2);
        float V2 = fmaf(dxb, fmaf(dxa, 1.f/6.f, A1a * 0.5f), A2);
        float h2 = fmaf(dxa, 0.5f, A1a);
#define S4(Q,C) { float u3 = fmaf(dxv.Q.C, U2, A3.Q.C); \
                  ac0.Q.C = fmaf(u3, qd.x, ac0.Q.C); \
                  ac1.Q.C = fmaf(u3, qd.y, ac1.Q.C); \
                  ac2.Q.C = fmaf(u3, qd.z, ac2.Q.C); \
                  ac3.Q.C = fmaf(u3, qd.w, ac3.Q.C); \
                  A3.Q.C = fmaf(dxv.Q.C, V2, A3.Q.C); }
        EACH(S4)
#undef S4
        A2 = fmaf(dxb, h2, A2);
        A1a += dxa;
    }

    if (ATOMIC) {
        float* o = dst + t * 256 + g * 4;
#define STA(J,Q,C) { atomicAdd(o + (J)*16 + 0, ac0.Q.C); atomicAdd(o + (J)*16 + 1, ac1.Q.C); \
                     atomicAdd(o + (J)*16 + 2, ac2.Q.C); atomicAdd(o + (J)*16 + 3, ac3.Q.C); }
        EACHI(STA)
#undef STA
    } else {
        float* o = dst + (size_t)cb * L4 + t * 256 + g * 4;
#define STO(J,Q,C) *reinterpret_cast<float4*>(o + (J)*16) = \
                       make_float4(ac0.Q.C, ac1.Q.C, ac2.Q.C, ac3.Q.C);
        EACHI(STO)
#undef STO
    }
}

// ------------- sum per-chunk level-4 partials -------------
__global__ __launch_bounds__(256) void k_reduce4(const float* __restrict__ partials,
                                                 float* __restrict__ out4) {
    const int i = blockIdx.x * 256 + threadIdx.x;  // 0..65535
    float s = 0.f;
#pragma unroll 8
    for (int c = 0; c < NC; ++c) s += partials[(size_t)c * L4 + i];
    out4[i] = s;
}

extern "C" void kernel_launch(void* const* d_in, const int* in_sizes, int n_in,
                              void* d_out, int out_size, void* d_ws, size_t ws_size,
                              hipStream_t stream) {
    const float* x = (const float*)d_in[0];
    float* out = (float*)d_out;
    float* ws = (float*)d_ws;

    float* dx = ws;                                   // 65536 floats
    float* chunk_sig = ws + 65536;                    // NC * SIG13
    float* prefix_sig = chunk_sig + NC * SIG13;       // NC * SIG13
    float* partials = prefix_sig + NC * SIG13;        // NC * L4
    const size_t need_bytes =
        ((size_t)65536 + 2ull * NC * SIG13 + (size_t)NC * L4) * sizeof(float);

    k_dx<<<dim3((NSTEP * DIMV + 255) / 256), dim3(256), 0, stream>>>(x, dx);
    k_chunk_sig<<<dim3(NC), dim3(256), 0, stream>>>(dx, chunk_sig);
    k_prefix<<<dim3(1), dim3(256), 0, stream>>>(chunk_sig, prefix_sig, out);

    if (ws_size >= need_bytes) {
        k_scan4<false><<<dim3(NC, 4), dim3(256), 0, stream>>>(dx, prefix_sig, partials);
        k_reduce4<<<dim3(256), dim3(256), 0, stream>>>(partials, out + SIG13);
    } else {
        hipMemsetAsync(out + SIG13, 0, (size_t)L4 * sizeof(float), stream);
        k_scan4<true><<<dim3(NC, 4), dim3(256), 0, stream>>>(dx, prefix_sig, out + SIG13);
    }
}

// Round 3
// 75.627 us; speedup vs baseline: 1.8664x; 1.8201x over previous
//
#include <hip/hip_runtime.h>

#define DIMV 16
#define NSTEP 4095      // 4096 - 1 increments
#define NC 64           // chunks
#define TSTEP 64        // ceil(NSTEP / NC)
#define SIG13 4368      // 16 + 256 + 4096
#define L4 65536        // 16^4

// 16-wide register vector as 4 explicit float4s — never runtime-indexed (rule #20).
struct V16 { float4 a, b, c, d; };

#define EACH(OP) OP(a,x) OP(a,y) OP(a,z) OP(a,w) OP(b,x) OP(b,y) OP(b,z) OP(b,w) \
                 OP(c,x) OP(c,y) OP(c,z) OP(c,w) OP(d,x) OP(d,y) OP(d,z) OP(d,w)
#define EACHI(OP) OP(0,a,x) OP(1,a,y) OP(2,a,z) OP(3,a,w) \
                  OP(4,b,x) OP(5,b,y) OP(6,b,z) OP(7,b,w) \
                  OP(8,c,x) OP(9,c,y) OP(10,c,z) OP(11,c,w) \
                  OP(12,d,x) OP(13,d,y) OP(14,d,z) OP(15,d,w)

__device__ inline V16 ldv16(const float* p) {
    const float4* q = reinterpret_cast<const float4*>(p);
    V16 v; v.a = q[0]; v.b = q[1]; v.c = q[2]; v.d = q[3]; return v;
}
__device__ inline void stv16(float* p, const V16& v) {
    float4* q = reinterpret_cast<float4*>(p);
    q[0] = v.a; q[1] = v.b; q[2] = v.c; q[3] = v.d;
}
__device__ inline V16 zerov16() {
    V16 v; v.a = v.b = v.c = v.d = make_float4(0.f, 0.f, 0.f, 0.f); return v;
}

// ---------------- dx = diff(x) ----------------
__global__ void k_dx(const float* __restrict__ x, float* __restrict__ dx) {
    int i = blockIdx.x * blockDim.x + threadIdx.x;
    if (i < NSTEP * DIMV) dx[i] = x[i + DIMV] - x[i];
}

// ------------- per-chunk LOCAL signature, levels 1-3, from zero -------------
__global__ __launch_bounds__(256, 1) void k_chunk_sig(const float* __restrict__ dx,
                                                      float* __restrict__ chunk_sig) {
    const int cb = blockIdx.x;
    const int t = threadIdx.x;
    const int ia = t >> 4, ib = t & 15;
    float A1a = 0.f, A2 = 0.f;
    V16 A3 = zerov16();

    const int s0 = cb * TSTEP;
    const int s1 = (s0 + TSTEP < NSTEP) ? (s0 + TSTEP) : NSTEP;
    for (int s = s0; s < s1; ++s) {
        const float* row = dx + s * DIMV;
        V16 dxv = ldv16(row);
        float dxa = row[ia];
        float dxb = row[ib];
        float V2 = fmaf(dxb, fmaf(dxa, 1.f/6.f, 0.5f * A1a), A2);
        float h2 = fmaf(dxa, 0.5f, A1a);
#define CS(Q,C) A3.Q.C = fmaf(dxv.Q.C, V2, A3.Q.C);
        EACH(CS)
#undef CS
        A2 = fmaf(dxb, h2, A2);
        A1a += dxa;
    }
    float* o = chunk_sig + (size_t)cb * SIG13;
    if (ib == 0) o[ia] = A1a;
    o[16 + t] = A2;
    stv16(o + 272 + t * 16, A3);
}

// ------------- parallel cascaded prefix: levels 1 & 2 -------------
// P1_c = prefix of S1; P2_c = prefix of (L2_c + P1_c (x) S1_c).
// One block, 256 threads. Writes exclusive prefixes into prefix_sig[c] and
// inclusive finals into out13.
__global__ __launch_bounds__(256, 1) void k_prefix12(const float* __restrict__ chunk_sig,
                                                     float* __restrict__ prefix_sig,
                                                     float* __restrict__ out13) {
    __shared__ float s1[NC][16];
    __shared__ float p1[NC][16];
    const int t = threadIdx.x;
    // load S1 of all chunks into LDS (4 passes of 16 chunks)
#pragma unroll
    for (int base = 0; base < NC; base += 16) {
        int c = base + (t >> 4);
        s1[c][t & 15] = chunk_sig[(size_t)c * SIG13 + (t & 15)];
    }
    __syncthreads();
    // P1 exclusive prefix (threads 0..15, element e = t)
    if (t < 16) {
        float p = 0.f;
        for (int c = 0; c < NC; ++c) {
            p1[c][t] = p;
            prefix_sig[(size_t)c * SIG13 + t] = p;
            p += s1[c][t];
        }
        out13[t] = p;
    }
    __syncthreads();
    // P2 prefix: thread t = (a,b); 8-deep prefetch of L2_c[t]
    const int a = t >> 4, b = t & 15;
    float pl0 = chunk_sig[0ul * SIG13 + 16 + t];
    float pl1 = chunk_sig[1ul * SIG13 + 16 + t];
    float pl2 = chunk_sig[2ul * SIG13 + 16 + t];
    float pl3 = chunk_sig[3ul * SIG13 + 16 + t];
    float pl4 = chunk_sig[4ul * SIG13 + 16 + t];
    float pl5 = chunk_sig[5ul * SIG13 + 16 + t];
    float pl6 = chunk_sig[6ul * SIG13 + 16 + t];
    float pl7 = chunk_sig[7ul * SIG13 + 16 + t];
    float p = 0.f;
    for (int cb = 0; cb < NC; cb += 8) {
#define STEP2(J) { int c = cb + J; \
        prefix_sig[(size_t)c * SIG13 + 16 + t] = p; \
        p = fmaf(p1[c][a], s1[c][b], p + pl##J); \
        int cn = c + 8; \
        if (cn < NC) pl##J = chunk_sig[(size_t)cn * SIG13 + 16 + t]; }
        STEP2(0) STEP2(1) STEP2(2) STEP2(3) STEP2(4) STEP2(5) STEP2(6) STEP2(7)
#undef STEP2
    }
    out13[16 + t] = p;
}

// ------------- parallel prefix: level 3 -------------
// P3_c = prefix of (L3_c + P1_c (x) L2_c + P2_c (x) S1_c).
// Grid 16 blocks (a = blockIdx), 256 threads (t = b*16 + c3).
__global__ __launch_bounds__(256, 1) void k_prefix3(const float* __restrict__ chunk_sig,
                                                    float* __restrict__ prefix_sig,
                                                    float* __restrict__ out13) {
    const int a = blockIdx.x;
    const int t = threadIdx.x;
    const int c3 = t & 15;
    const size_t off3 = 272 + (size_t)a * 256 + t;   // L3/P3 element offset in a sig
    // 4-deep prefetch buffers (static names, no runtime indexing)
#define LOADC(J, C) \
    float l3_##J = chunk_sig[(size_t)(C) * SIG13 + off3]; \
    float l2_##J = chunk_sig[(size_t)(C) * SIG13 + 16 + t]; \
    float s1_##J = chunk_sig[(size_t)(C) * SIG13 + c3]; \
    float pa_##J = prefix_sig[(size_t)(C) * SIG13 + a]; \
    float pb_##J = prefix_sig[(size_t)(C) * SIG13 + 16 + (a << 4) + (t >> 4)];
#define RELOADC(J, C) { int cc = (C); if (cc < NC) { \
    l3_##J = chunk_sig[(size_t)cc * SIG13 + off3]; \
    l2_##J = chunk_sig[(size_t)cc * SIG13 + 16 + t]; \
    s1_##J = chunk_sig[(size_t)cc * SIG13 + c3]; \
    pa_##J = prefix_sig[(size_t)cc * SIG13 + a]; \
    pb_##J = prefix_sig[(size_t)cc * SIG13 + 16 + (a << 4) + (t >> 4)]; } }
    LOADC(0, 0) LOADC(1, 1) LOADC(2, 2) LOADC(3, 3)
    float p = 0.f;
    for (int cb = 0; cb < NC; cb += 4) {
#define STEP3(J) { int c = cb + J; \
        prefix_sig[(size_t)c * SIG13 + off3] = p; \
        p = p + l3_##J + fmaf(pa_##J, l2_##J, pb_##J * s1_##J); \
        RELOADC(J, c + 4) }
        STEP3(0) STEP3(1) STEP3(2) STEP3(3)
#undef STEP3
    }
    out13[off3] = p;
#undef LOADC
#undef RELOADC
}

// ------------- level-4 accumulation: re-scan chunk from true prefix -------------
template <bool ATOMIC>
__global__ __launch_bounds__(256, 1) void k_scan4(const float* __restrict__ dx,
                                                  const float* __restrict__ prefix_sig,
                                                  float* __restrict__ dst) {
    const int cb = blockIdx.x;
    const int g = blockIdx.y;   // 0..3 : d-group
    const int t = threadIdx.x;
    const int ia = t >> 4, ib = t & 15;

    const float* P = prefix_sig + (size_t)cb * SIG13;
    float A1a = P[ia];
    float A2 = P[16 + t];
    V16 A3 = ldv16(P + 272 + t * 16);
    V16 ac0 = zerov16(), ac1 = zerov16(), ac2 = zerov16(), ac3 = zerov16();

    const int s0 = cb * TSTEP;
    const int s1 = (s0 + TSTEP < NSTEP) ? (s0 + TSTEP) : NSTEP;
    for (int s = s0; s < s1; ++s) {
        const float* row = dx + s * DIMV;
        V16 dxv = ldv16(row);
        float dxa = row[ia];
        float dxb = row[ib];
        float4 qd = *reinterpret_cast<const float4*>(row + g * 4);

        float U2 = fmaf(dxb, fmaf(dxa, 1.f/24.f, A1a * (1.f/6.f)), 0.5f * A2);
        float V2 = fmaf(dxb, fmaf(dxa, 1.f/6.f, A1a * 0.5f), A2);
        float h2 = fmaf(dxa, 0.5f, A1a);
#define S4(Q,C) { float u3 = fmaf(dxv.Q.C, U2, A3.Q.C); \
                  ac0.Q.C = fmaf(u3, qd.x, ac0.Q.C); \
                  ac1.Q.C = fmaf(u3, qd.y, ac1.Q.C); \
                  ac2.Q.C = fmaf(u3, qd.z, ac2.Q.C); \
                  ac3.Q.C = fmaf(u3, qd.w, ac3.Q.C); \
                  A3.Q.C = fmaf(dxv.Q.C, V2, A3.Q.C); }
        EACH(S4)
#undef S4
        A2 = fmaf(dxb, h2, A2);
        A1a += dxa;
    }

    if (ATOMIC) {
        float* o = dst + t * 256 + g * 4;
#define STA(J,Q,C) { atomicAdd(o + (J)*16 + 0, ac0.Q.C); atomicAdd(o + (J)*16 + 1, ac1.Q.C); \
                     atomicAdd(o + (J)*16 + 2, ac2.Q.C); atomicAdd(o + (J)*16 + 3, ac3.Q.C); }
        EACHI(STA)
#undef STA
    } else {
        float* o = dst + (size_t)cb * L4 + t * 256 + g * 4;
#define STO(J,Q,C) *reinterpret_cast<float4*>(o + (J)*16) = \
                       make_float4(ac0.Q.C, ac1.Q.C, ac2.Q.C, ac3.Q.C);
        EACHI(STO)
#undef STO
    }
}

// ------------- sum per-chunk level-4 partials -------------
__global__ __launch_bounds__(256) void k_reduce4(const float* __restrict__ partials,
                                                 float* __restrict__ out4) {
    const int i = blockIdx.x * 256 + threadIdx.x;  // 0..65535
    float s = 0.f;
#pragma unroll 8
    for (int c = 0; c < NC; ++c) s += partials[(size_t)c * L4 + i];
    out4[i] = s;
}

extern "C" void kernel_launch(void* const* d_in, const int* in_sizes, int n_in,
                              void* d_out, int out_size, void* d_ws, size_t ws_size,
                              hipStream_t stream) {
    const float* x = (const float*)d_in[0];
    float* out = (float*)d_out;
    float* ws = (float*)d_ws;

    float* dx = ws;                                   // 65536 floats
    float* chunk_sig = ws + 65536;                    // NC * SIG13
    float* prefix_sig = chunk_sig + NC * SIG13;       // NC * SIG13
    float* partials = prefix_sig + NC * SIG13;        // NC * L4
    const size_t need_bytes =
        ((size_t)65536 + 2ull * NC * SIG13 + (size_t)NC * L4) * sizeof(float);

    k_dx<<<dim3((NSTEP * DIMV + 255) / 256), dim3(256), 0, stream>>>(x, dx);
    k_chunk_sig<<<dim3(NC), dim3(256), 0, stream>>>(dx, chunk_sig);
    k_prefix12<<<dim3(1), dim3(256), 0, stream>>>(chunk_sig, prefix_sig, out);
    k_prefix3<<<dim3(16), dim3(256), 0, stream>>>(chunk_sig, prefix_sig, out);

    if (ws_size >= need_bytes) {
        k_scan4<false><<<dim3(NC, 4), dim3(256), 0, stream>>>(dx, prefix_sig, partials);
        k_reduce4<<<dim3(256), dim3(256), 0, stream>>>(partials, out + SIG13);
    } else {
        hipMemsetAsync(out + SIG13, 0, (size_t)L4 * sizeof(float), stream);
        k_scan4<true><<<dim3(NC, 4), dim3(256), 0, stream>>>(dx, prefix_sig, out + SIG13);
    }
}